// Round 14
// baseline (253.560 us; speedup 1.0000x reference)
//
#include <hip/hip_runtime.h>

#define HH 512
#define WW 512
#define NB 4

typedef unsigned short u16;
typedef __attribute__((ext_vector_type(8))) short bf16x8;    // 8 bf16 = 4 VGPR
typedef __attribute__((ext_vector_type(16))) float f32x16;   // 32x32 acc

static __device__ __forceinline__ float bf2f(u16 b) {
  return __uint_as_float(((unsigned)b) << 16);
}
static __device__ __forceinline__ u16 f2bf(float f) {
  unsigned u = __float_as_uint(f);
  u += 0x7fffu + ((u >> 16) & 1u);
  return (u16)(u >> 16);
}

// ---------------------------------------------------------------- rulebook (+pool flags)
__global__ __launch_bounds__(256) void build_grid_mark(const int* __restrict__ coords,
                                                       int n, int* __restrict__ grid,
                                                       int* __restrict__ flags) {
  int i = blockIdx.x * 256 + threadIdx.x;
  if (i >= n) return;
  int b = coords[3*i], y = coords[3*i+1], x = coords[3*i+2];
  grid[(b * HH + y) * WW + x] = i;
  flags[(b << 16) | ((y >> 1) << 8) | (x >> 1)] = 1;
}

// ------------------------------------------------- feats f32 -> bf16 (+zero row n)
__global__ __launch_bounds__(256) void cvt_feats(const float* __restrict__ in,
                                                 u16* __restrict__ out, int n) {
  long i = (long)blockIdx.x * 256 + threadIdx.x;   // one ushort4 (4 elems) each
  long total = (long)n * 16;                        // n*64/4
  if (i < total) {
    float4 v = reinterpret_cast<const float4*>(in)[i];
    ushort4 o;
    o.x = f2bf(v.x); o.y = f2bf(v.y); o.z = f2bf(v.z); o.w = f2bf(v.w);
    reinterpret_cast<ushort4*>(out)[i] = o;
  } else if (i < total + 16) {                      // zero row n (64 ch)
    reinterpret_cast<ushort4*>(out)[i] = make_ushort4(0, 0, 0, 0);
  }
}

// ------------------------------------------------- W [9][CI][128] f32 -> packed bf16
// 32x32x16 fragment order. t = ((s*8 + sub)*64 + l)*8 + j, sub = ksub*4 + ct.
// kappa = s*32 + ksub*16 + (l>>5)*8 + j ; col = ct*32 + (l&31).
template<int CI>
__global__ __launch_bounds__(256) void pack_w(const float* __restrict__ Wt,
                                              u16* __restrict__ out) {
  int t = blockIdx.x * 256 + threadIdx.x;           // total = 9*CI*128, exact grid
  int j   = t & 7;
  int l   = (t >> 3) & 63;
  int sub = (t >> 9) & 7;
  int s   = t >> 12;
  int kappa = s * 32 + (sub >> 2) * 16 + (l >> 5) * 8 + j;
  int col   = (sub & 3) * 32 + (l & 31);
  out[t] = f2bf(Wt[(size_t)kappa * 128 + col]);
}

// ---------------------------------------------------------------- MFMA conv
// r10 tiling (block 256x128, 4 waves x 64 rows x 128 cols, acc[2][4] f32x16,
// 32x32x16 MFMA, K step 32) with NEW staging:
//  - B via global_load_lds, staged TWO steps ahead into a 3 x 8KB ring
//    (frees the B reg-staging VGPRs of r10),
//  - A gathered per-lane 16B on a DEPTH-2 register queue (A(s) issued at
//    iter s-2 -> ~2 step-periods of L3 latency budget; r10's depth-1 bound
//    the period at one gather latency = the 37.6% MfmaUtil knee),
//  - barrier uses counted vmcnt from in-order retirement: ops issued after
//    stage(s+1) are A(s+1)[4]+stage(s+2)[2]+A(s+2)[4] = 10 -> vmcnt(10)
//    retires exactly stage(s+1) for every wave before s_barrier (tail
//    iterations: vmcnt(4) / none; guards fold at full unroll).
// ~112 VGPR + 128 AGPR <= 256 -> 2 waves/SIMD (__launch_bounds__(256,2)).
template<int CI>
__global__ __launch_bounds__(256, 2) void conv_mfma(
    const u16* __restrict__ inb,      // bf16 [n+1][CI], row n zeros
    const u16* __restrict__ Wp,       // packed bf16 [K/32][8][64][8]
    const float* __restrict__ bias,   // [128]
    const int* __restrict__ coords,
    const int* __restrict__ grid,
    u16* __restrict__ outb,           // bf16 [n][128] raw conv output (+bias)
    float* __restrict__ pbuf,         // [2][128][nblk] col stats partials
    int n)
{
  constexpr int KSTEPS = 9 * CI / 32;  // 18 / 36
  constexpr int KPERK  = CI / 32;      // K-steps per 3x3 offset
  constexpr int CBYTES = CI * 2;
  __shared__ u16 sB[3][4096];          // 3 x 8KB ring
  __shared__ float sred[2][4][4][32];

  const int tid  = threadIdx.x;
  const int w    = tid >> 6;
  const int lane = tid & 63;
  const int l31  = lane & 31;
  const int hi   = lane >> 5;

  // XCD-bijective swizzle (gridDim % 8 == 0)
  const int bid  = blockIdx.x;
  const int nblk = (int)gridDim.x;
  const int swz  = (bid & 7) * (nblk >> 3) + (bid >> 3);
  const int row0 = swz * 256;

  // per-lane rulebook: 2 row-subtiles x 9 neighbor byte-offsets
  unsigned voff[2][9];
  #pragma unroll
  for (int rt = 0; rt < 2; ++rt) {
    int myrow = row0 + w * 64 + rt * 32 + l31;
    int b = coords[3*myrow], y = coords[3*myrow+1], x = coords[3*myrow+2];
    #pragma unroll
    for (int k = 0; k < 9; ++k) {
      int ny = y - (k / 3 - 1);
      int nx = x - (k % 3 - 1);
      int src = n;                                  // zero row
      if (ny >= 0 && ny < HH && nx >= 0 && nx < WW) {
        int g = grid[(b * HH + ny) * WW + nx];
        if (g >= 0) src = g;
      }
      voff[rt][k] = (unsigned)src * CBYTES + hi * 16;
    }
  }

  const char* wbase = (const char*)Wp;
  auto stage = [&](int s, int buf) {               // 2 x global_load_lds 16B / wave
    const char* g = wbase + (size_t)s * 8192 + w * 2048 + lane * 16;
    char* l = (char*)&sB[buf][0] + w * 2048;
    __builtin_amdgcn_global_load_lds(
        (const __attribute__((address_space(1))) unsigned int*)(g),
        (__attribute__((address_space(3))) unsigned int*)(l), 16, 0, 0);
    __builtin_amdgcn_global_load_lds(
        (const __attribute__((address_space(1))) unsigned int*)(g + 1024),
        (__attribute__((address_space(3))) unsigned int*)(l + 1024), 16, 0, 0);
  };
  const char* abase = (const char*)inb;
  auto loadA = [&](int s, int rt, int ksub) -> bf16x8 {
    int k = s / KPERK, c32 = s % KPERK;              // compile-time under unroll
    return *reinterpret_cast<const bf16x8*>(abase + voff[rt][k] + c32 * 64 + ksub * 32);
  };

  f32x16 acc[2][4];
  #pragma unroll
  for (int rt = 0; rt < 2; ++rt)
    #pragma unroll
    for (int ct = 0; ct < 4; ++ct)
      #pragma unroll
      for (int r = 0; r < 16; ++r) acc[rt][ct][r] = 0.f;

  // prologue: stage(0),stage(1); A(0),A(1) queued; retire stage(0) only
  stage(0, 0);
  stage(1, 1);
  bf16x8 aq0[2][2], aq1[2][2];
  #pragma unroll
  for (int rt = 0; rt < 2; ++rt) {
    aq0[rt][0] = loadA(0, rt, 0); aq0[rt][1] = loadA(0, rt, 1);
  }
  #pragma unroll
  for (int rt = 0; rt < 2; ++rt) {
    aq1[rt][0] = loadA(1, rt, 0); aq1[rt][1] = loadA(1, rt, 1);
  }
  asm volatile("s_waitcnt vmcnt(10)" ::: "memory");   // ops after stage(0) = 10
  asm volatile("s_barrier" ::: "memory");

  #pragma unroll
  for (int s = 0; s < KSTEPS; ++s) {
    const int cur = s % 3;
    if (s + 2 < KSTEPS) stage(s + 2, (s + 2) % 3);
    bf16x8 na[2][2] = {};
    if (s + 2 < KSTEPS) {
      #pragma unroll
      for (int rt = 0; rt < 2; ++rt) {
        na[rt][0] = loadA(s + 2, rt, 0); na[rt][1] = loadA(s + 2, rt, 1);
      }
    }

    bf16x8 bb0[4];
    #pragma unroll
    for (int f = 0; f < 4; ++f)
      bb0[f] = *reinterpret_cast<const bf16x8*>(&sB[cur][f * 512 + lane * 8]);

    __builtin_amdgcn_s_setprio(1);
    #pragma unroll
    for (int ct = 0; ct < 4; ++ct) {
      acc[0][ct] = __builtin_amdgcn_mfma_f32_32x32x16_bf16(aq0[0][0], bb0[ct], acc[0][ct], 0, 0, 0);
      acc[1][ct] = __builtin_amdgcn_mfma_f32_32x32x16_bf16(aq0[1][0], bb0[ct], acc[1][ct], 0, 0, 0);
    }
    bf16x8 bb1[4];
    #pragma unroll
    for (int f = 0; f < 4; ++f)
      bb1[f] = *reinterpret_cast<const bf16x8*>(&sB[cur][(4 + f) * 512 + lane * 8]);
    #pragma unroll
    for (int ct = 0; ct < 4; ++ct) {
      acc[0][ct] = __builtin_amdgcn_mfma_f32_32x32x16_bf16(aq0[0][1], bb1[ct], acc[0][ct], 0, 0, 0);
      acc[1][ct] = __builtin_amdgcn_mfma_f32_32x32x16_bf16(aq0[1][1], bb1[ct], acc[1][ct], 0, 0, 0);
    }
    __builtin_amdgcn_s_setprio(0);

    // barrier: retire stage(s+1) (read next iter by ALL waves) while leaving
    // A(s+1) + stage(s+2) + A(s+2) in flight (depth-2 latency hiding).
    if (s + 2 < KSTEPS) {
      asm volatile("s_waitcnt vmcnt(10)" ::: "memory");
      asm volatile("s_barrier" ::: "memory");
    } else if (s + 1 < KSTEPS) {
      asm volatile("s_waitcnt vmcnt(4)" ::: "memory");
      asm volatile("s_barrier" ::: "memory");
    }
    #pragma unroll
    for (int rt = 0; rt < 2; ++rt) {
      aq0[rt][0] = aq1[rt][0]; aq0[rt][1] = aq1[rt][1];
      aq1[rt][0] = na[rt][0];  aq1[rt][1] = na[rt][1];
    }
  }

  // epilogue: bias + store + fused BN stats partials
  // C/D: col = ct*32 + l31, row = row0 + w*64 + rt*32 + (reg&3) + 8*(reg>>2) + 4*hi
  #pragma unroll
  for (int ct = 0; ct < 4; ++ct) {
    int col = ct * 32 + l31;
    float bv = bias[col];
    float s = 0.f, q = 0.f;
    #pragma unroll
    for (int rt = 0; rt < 2; ++rt)
      #pragma unroll
      for (int reg = 0; reg < 16; ++reg) {
        int row = row0 + w * 64 + rt * 32 + (reg & 3) + 8 * (reg >> 2) + 4 * hi;
        float v = acc[rt][ct][reg] + bv;
        outb[(size_t)row * 128 + col] = f2bf(v);
        s += v; q = fmaf(v, v, q);
      }
    s += __shfl_xor(s, 32); q += __shfl_xor(q, 32);
    if (hi == 0) { sred[0][w][ct][l31] = s; sred[1][w][ct][l31] = q; }
  }
  __syncthreads();
  if (tid < 128) {                     // col == tid
    int ct = tid >> 5, c = tid & 31;
    float s = sred[0][0][ct][c] + sred[0][1][ct][c] +
              sred[0][2][ct][c] + sred[0][3][ct][c];
    float q = sred[1][0][ct][c] + sred[1][1][ct][c] +
              sred[1][2][ct][c] + sred[1][3][ct][c];
    pbuf[(size_t)tid * nblk + bid]         = s;
    pbuf[(size_t)(128 + tid) * nblk + bid] = q;
  }
}

// ------------------------------------------------- reduce stats partials + BN finalize
__global__ __launch_bounds__(256) void reduce_final(const float* __restrict__ pbuf,
                                                    int nblk,
                                                    const float* __restrict__ g,
                                                    const float* __restrict__ be,
                                                    int n,
                                                    float* __restrict__ scale,
                                                    float* __restrict__ shiftv) {
  const int c = blockIdx.x;
  const float* ps = pbuf + (size_t)c * nblk;
  const float* pq = pbuf + (size_t)(128 + c) * nblk;
  float s = 0.f, q = 0.f;
  for (int i = threadIdx.x; i < nblk; i += 256) { s += ps[i]; q += pq[i]; }
  __shared__ float ls[256], lq[256];
  ls[threadIdx.x] = s; lq[threadIdx.x] = q;
  __syncthreads();
  for (int o = 128; o > 0; o >>= 1) {
    if (threadIdx.x < o) {
      ls[threadIdx.x] += ls[threadIdx.x + o];
      lq[threadIdx.x] += lq[threadIdx.x + o];
    }
    __syncthreads();
  }
  if (threadIdx.x == 0) {
    float inv_n = 1.f / (float)n;
    float mu  = ls[0] * inv_n;
    float var = lq[0] * inv_n - mu * mu;
    float sc  = g[c] * rsqrtf(var + 1e-5f);
    scale[c]  = sc;
    shiftv[c] = be[c] - mu * sc;
  }
}

// ------------------------------------------------- in-place BN+ReLU on bf16 [n][128]
__global__ __launch_bounds__(256) void apply_bn(u16* __restrict__ f,
                                                const float* __restrict__ scale,
                                                const float* __restrict__ shiftv,
                                                int n) {
  long i = (long)blockIdx.x * 256 + threadIdx.x;   // one uint4 (8 elems) each
  long total = (long)n * 16;                        // n*128/8
  uint4* p = reinterpret_cast<uint4*>(f);
  if (i < total) {
    uint4 u = p[i];
    int c0 = (int)(i & 15) * 8;
    unsigned in4[4] = {u.x, u.y, u.z, u.w};
    unsigned r4[4];
    #pragma unroll
    for (int q = 0; q < 4; ++q) {
      float lo = bf2f((u16)(in4[q] & 0xffffu));
      float hi = bf2f((u16)(in4[q] >> 16));
      lo = fmaxf(lo * scale[c0 + 2*q]     + shiftv[c0 + 2*q],     0.f);
      hi = fmaxf(hi * scale[c0 + 2*q + 1] + shiftv[c0 + 2*q + 1], 0.f);
      r4[q] = (unsigned)f2bf(lo) | ((unsigned)f2bf(hi) << 16);
    }
    p[i] = make_uint4(r4[0], r4[1], r4[2], r4[3]);
  } else if (i < total + 16) {                      // zero row n (128 ch)
    p[i] = make_uint4(0, 0, 0, 0);
  }
}

// ---------------------------------------------------------------- pooling
__global__ __launch_bounds__(256) void scan_bsum(const int* __restrict__ flags,
                                                 int* __restrict__ bsum) {
  __shared__ int s[256];
  int t = threadIdx.x;
  s[t] = flags[blockIdx.x * 256 + t];
  __syncthreads();
  for (int o = 128; o > 0; o >>= 1) {
    if (t < o) s[t] += s[t + o];
    __syncthreads();
  }
  if (t == 0) bsum[blockIdx.x] = s[0];
}

__global__ __launch_bounds__(1024) void scan_offsets(const int* __restrict__ bsum,
                                                     int* __restrict__ boff) {
  __shared__ int s[1024];
  int t = threadIdx.x;
  int orig = bsum[t];
  s[t] = orig;
  __syncthreads();
  for (int o = 1; o < 1024; o <<= 1) {
    int v = (t >= o) ? s[t - o] : 0;
    __syncthreads();
    s[t] += v;
    __syncthreads();
  }
  boff[t] = s[t] - orig;   // exclusive
}

__global__ __launch_bounds__(256) void emit_uniq(const int* __restrict__ flags,
                                                 const int* __restrict__ boff,
                                                 int* __restrict__ cellOf,
                                                 float* __restrict__ out_uniq) {
  __shared__ int s[256];
  int t = threadIdx.x;
  int cell = blockIdx.x * 256 + t;
  int f = flags[cell];
  s[t] = f;
  __syncthreads();
  for (int o = 1; o < 256; o <<= 1) {
    int v = (t >= o) ? s[t - o] : 0;
    __syncthreads();
    s[t] += v;
    __syncthreads();
  }
  if (f) {
    int r = boff[blockIdx.x] + s[t] - f;
    cellOf[r] = cell;
    out_uniq[(size_t)r * 3 + 0] = (float)(cell >> 16);
    out_uniq[(size_t)r * 3 + 1] = (float)((cell >> 8) & 255);
    out_uniq[(size_t)r * 3 + 2] = (float)(cell & 255);
  }
}

// rank-compacted max pool: 16 lanes per cell, ushort8 (16B) row loads,
// grid-stride over ranks. BN applied via slope-sign max/min select.
__global__ __launch_bounds__(256) void pool2(const int* __restrict__ cellOf,
                                             const int* __restrict__ grid,
                                             const u16* __restrict__ f2,
                                             const float* __restrict__ scale,
                                             const float* __restrict__ shiftv,
                                             float* __restrict__ out_pooled, int U) {
  __shared__ float s_sc[128], s_sh[128];
  for (int c = threadIdx.x; c < 128; c += 256) { s_sc[c] = scale[c]; s_sh[c] = shiftv[c]; }
  __syncthreads();
  const int cslot = threadIdx.x >> 4;
  const int l16   = threadIdx.x & 15;
  const int c0    = l16 * 8;
  for (int base = blockIdx.x * 16; base < U; base += (int)gridDim.x * 16) {
    int rank = base + cslot;
    if (rank >= U) continue;
    int cell = cellOf[rank];
    int b = cell >> 16, y2 = (cell >> 8) & 255, x2 = cell & 255;
    int gb = (b * HH + y2 * 2) * WW + x2 * 2;
    int ss[4];
    ss[0] = grid[gb];      ss[1] = grid[gb + 1];
    ss[2] = grid[gb + WW]; ss[3] = grid[gb + WW + 1];
    float mx[8], mn[8];
    #pragma unroll
    for (int j = 0; j < 8; ++j) { mx[j] = -3.4e38f; mn[j] = 3.4e38f; }
    #pragma unroll
    for (int d = 0; d < 4; ++d) {
      int s = ss[d];
      if (s < 0) continue;
      uint4 u = *reinterpret_cast<const uint4*>(f2 + (size_t)s * 128 + c0);
      unsigned uu[4] = {u.x, u.y, u.z, u.w};
      #pragma unroll
      for (int q = 0; q < 4; ++q) {
        float lo = bf2f((u16)(uu[q] & 0xffffu));
        float hi = bf2f((u16)(uu[q] >> 16));
        mx[2*q]   = fmaxf(mx[2*q], lo);   mn[2*q]   = fminf(mn[2*q], lo);
        mx[2*q+1] = fmaxf(mx[2*q+1], hi); mn[2*q+1] = fminf(mn[2*q+1], hi);
      }
    }
    float o[8];
    #pragma unroll
    for (int j = 0; j < 8; ++j) {
      float sc = s_sc[c0 + j], sh = s_sh[c0 + j];
      float v = (sc >= 0.f) ? mx[j] : mn[j];
      o[j] = fmaxf(v * sc + sh, 0.f);
    }
    float4* op = reinterpret_cast<float4*>(out_pooled + (size_t)rank * 128 + c0);
    op[0] = make_float4(o[0], o[1], o[2], o[3]);
    op[1] = make_float4(o[4], o[5], o[6], o[7]);
  }
}

// ---------------------------------------------------------------- launch
extern "C" void kernel_launch(void* const* d_in, const int* in_sizes, int n_in,
                              void* d_out, int out_size, void* d_ws, size_t ws_size,
                              hipStream_t stream) {
  (void)n_in; (void)ws_size;
  const int*   coords = (const int*)  d_in[0];
  const float* feats  = (const float*)d_in[1];
  const float* W1     = (const float*)d_in[2];
  const float* b1     = (const float*)d_in[3];
  const float* g1     = (const float*)d_in[4];
  const float* be1    = (const float*)d_in[5];
  const float* W2     = (const float*)d_in[6];
  const float* b2     = (const float*)d_in[7];
  const float* g2     = (const float*)d_in[8];
  const float* be2    = (const float*)d_in[9];

  const int n = in_sizes[0] / 3;          // 262144 (multiple of 256)
  const int U = out_size / 131;           // out = uniq (U,3) ++ pooled (U,128)
  const int nblk = n / 256;               // 1024

  char* wsp = (char*)d_ws;
  size_t off = 0;
  auto alloc = [&](size_t bytes) -> void* {
    void* p = wsp + off;
    off += (bytes + 255) & ~(size_t)255;
    return p;
  };
  int* grid = (int*)alloc(sizeof(int) * (size_t)NB * HH * WW);
  u16* f1   = (u16*)alloc(sizeof(u16) * (size_t)(n + 1) * 128);  // conv1 out / BN+ReLU in-place (+zero row)
  u16* breg = (u16*)alloc(sizeof(u16) * (size_t)n * 128);        // feats_bf first, later f2
  u16* fbf  = breg;                                              // bf16 feats [n+1][64]
  u16* f2   = breg;                                              // bf16 conv2 out [n][128]
  u16* Wp1  = (u16*)alloc(sizeof(u16) * 9 * 64 * 128);
  u16* Wp2  = (u16*)alloc(sizeof(u16) * 9 * 128 * 128);
  float* pbuf = (float*)alloc(sizeof(float) * 256 * (size_t)nblk);  // stats partials
  float* bnp  = (float*)alloc(sizeof(float) * 512);   // scale1 shift1 scale2 shift2
  int* flags  = (int*)alloc(sizeof(int) * (size_t)NB * 256 * 256);
  int* bsum   = (int*)alloc(sizeof(int) * 1024);
  int* boff   = (int*)alloc(sizeof(int) * 1024);
  int* cellOf = (int*)alloc(sizeof(int) * (size_t)n);

  float* scale1 = bnp,       *shift1 = bnp + 128;
  float* scale2 = bnp + 256, *shift2 = bnp + 384;

  hipMemsetAsync(grid, 0xFF, sizeof(int) * (size_t)NB * HH * WW, stream);
  hipMemsetAsync(flags, 0, sizeof(int) * (size_t)NB * 256 * 256, stream);

  build_grid_mark<<<(n + 255) / 256, 256, 0, stream>>>(coords, n, grid, flags);
  cvt_feats<<<(n * 16 + 16 + 255) / 256, 256, 0, stream>>>(feats, fbf, n);
  pack_w<64><<<9 * 64 * 128 / 256, 256, 0, stream>>>(W1, Wp1);
  pack_w<128><<<9 * 128 * 128 / 256, 256, 0, stream>>>(W2, Wp2);

  conv_mfma<64><<<nblk, 256, 0, stream>>>(fbf, Wp1, b1, coords, grid, f1, pbuf, n);
  reduce_final<<<128, 256, 0, stream>>>(pbuf, nblk, g1, be1, n, scale1, shift1);
  apply_bn<<<(n * 16 + 16 + 255) / 256, 256, 0, stream>>>(f1, scale1, shift1, n);

  conv_mfma<128><<<nblk, 256, 0, stream>>>(f1, Wp2, b2, coords, grid, f2, pbuf, n);
  reduce_final<<<128, 256, 0, stream>>>(pbuf, nblk, g2, be2, n, scale2, shift2);

  scan_bsum<<<1024, 256, 0, stream>>>(flags, bsum);
  scan_offsets<<<1, 1024, 0, stream>>>(bsum, boff);

  float* out_f = (float*)d_out;
  emit_uniq<<<1024, 256, 0, stream>>>(flags, boff, cellOf, out_f);
  pool2<<<2048, 256, 0, stream>>>(cellOf, grid, f2, scale2, shift2,
                                  out_f + (size_t)U * 3, U);
}

// Round 15
// 235.223 us; speedup vs baseline: 1.0780x; 1.0780x over previous
//
#include <hip/hip_runtime.h>

#define HH 512
#define WW 512
#define NB 4

typedef unsigned short u16;
typedef __attribute__((ext_vector_type(8))) short bf16x8;    // 8 bf16 = 4 VGPR
typedef __attribute__((ext_vector_type(16))) float f32x16;   // 32x32 acc

static __device__ __forceinline__ float bf2f(u16 b) {
  return __uint_as_float(((unsigned)b) << 16);
}
static __device__ __forceinline__ u16 f2bf(float f) {
  unsigned u = __float_as_uint(f);
  u += 0x7fffu + ((u >> 16) & 1u);
  return (u16)(u >> 16);
}

// ---------------------------------------------------------------- rulebook (+pool flags)
__global__ __launch_bounds__(256) void build_grid_mark(const int* __restrict__ coords,
                                                       int n, int* __restrict__ grid,
                                                       int* __restrict__ flags) {
  int i = blockIdx.x * 256 + threadIdx.x;
  if (i >= n) return;
  int b = coords[3*i], y = coords[3*i+1], x = coords[3*i+2];
  grid[(b * HH + y) * WW + x] = i;
  flags[(b << 16) | ((y >> 1) << 8) | (x >> 1)] = 1;
}

// ------------------------------------------------- feats f32 -> bf16 (+zero row n)
__global__ __launch_bounds__(256) void cvt_feats(const float* __restrict__ in,
                                                 u16* __restrict__ out, int n) {
  long i = (long)blockIdx.x * 256 + threadIdx.x;   // one ushort4 (4 elems) each
  long total = (long)n * 16;                        // n*64/4
  if (i < total) {
    float4 v = reinterpret_cast<const float4*>(in)[i];
    ushort4 o;
    o.x = f2bf(v.x); o.y = f2bf(v.y); o.z = f2bf(v.z); o.w = f2bf(v.w);
    reinterpret_cast<ushort4*>(out)[i] = o;
  } else if (i < total + 16) {                      // zero row n (64 ch)
    reinterpret_cast<ushort4*>(out)[i] = make_ushort4(0, 0, 0, 0);
  }
}

// ------------------------------------------------- W [9][CI][128] f32 -> packed bf16
// 32x32x16 fragment order. t = ((s*8 + sub)*64 + l)*8 + j, sub = ksub*4 + ct.
// kappa = s*32 + ksub*16 + (l>>5)*8 + j ; col = ct*32 + (l&31).
template<int CI>
__global__ __launch_bounds__(256) void pack_w(const float* __restrict__ Wt,
                                              u16* __restrict__ out) {
  int t = blockIdx.x * 256 + threadIdx.x;           // total = 9*CI*128, exact grid
  int j   = t & 7;
  int l   = (t >> 3) & 63;
  int sub = (t >> 9) & 7;
  int s   = t >> 12;
  int kappa = s * 32 + (sub >> 2) * 16 + (l >> 5) * 8 + j;
  int col   = (sub & 3) * 32 + (l & 31);
  out[t] = f2bf(Wt[(size_t)kappa * 128 + col]);
}

// ---------------------------------------------------------------- MFMA conv
// Block: 256 rows x 128 cols, 4 waves (each 64 rows x 128 cols, acc[2][4] f32x16).
// 32x32x16 MFMA, K stepped by 32. B slab (8KB) triple-buffered in LDS via
// REG-staging: global->reg 2 steps ahead, reg->LDS write before the barrier.
// A gathered per-lane 16B ONE step ahead (depth-1 queue) so VGPR+AGPR fits
// 256 -> 2 waves/SIMD, enforced by __launch_bounds__(256,2).
// Barrier = lgkmcnt(0)+s_barrier only; the compiler's pre-MFMA wait on A(s)
// becomes a counted vmcnt, leaving B(s+2)/A(s+1) in flight across the barrier.
template<int CI>
__global__ __launch_bounds__(256, 2) void conv_mfma(
    const u16* __restrict__ inb,      // bf16 [n+1][CI], row n zeros
    const u16* __restrict__ Wp,       // packed bf16 [K/32][8][64][8]
    const float* __restrict__ bias,   // [128]
    const int* __restrict__ coords,
    const int* __restrict__ grid,
    u16* __restrict__ outb,           // bf16 [n][128] raw conv output (+bias)
    float* __restrict__ pbuf,         // [2][128][nblk] col stats partials
    int n)
{
  constexpr int KSTEPS = 9 * CI / 32;
  constexpr int KPERK  = CI / 32;     // K-steps per 3x3 offset
  constexpr int CBYTES = CI * 2;
  __shared__ u16 sB[3][4096];         // 3 x 8KB
  __shared__ float sred[2][4][4][32];

  const int tid  = threadIdx.x;
  const int w    = tid >> 6;
  const int lane = tid & 63;
  const int l31  = lane & 31;
  const int hi   = lane >> 5;

  // XCD-bijective swizzle (gridDim % 8 == 0)
  const int bid  = blockIdx.x;
  const int nblk = (int)gridDim.x;
  const int swz  = (bid & 7) * (nblk >> 3) + (bid >> 3);
  const int row0 = swz * 256;

  // per-lane rulebook: 2 row-subtiles x 9 neighbor byte-offsets
  unsigned voff[2][9];
  #pragma unroll
  for (int rt = 0; rt < 2; ++rt) {
    int myrow = row0 + w * 64 + rt * 32 + l31;
    int b = coords[3*myrow], y = coords[3*myrow+1], x = coords[3*myrow+2];
    #pragma unroll
    for (int k = 0; k < 9; ++k) {
      int ny = y - (k / 3 - 1);
      int nx = x - (k % 3 - 1);
      int src = n;                                  // zero row
      if (ny >= 0 && ny < HH && nx >= 0 && nx < WW) {
        int g = grid[(b * HH + ny) * WW + nx];
        if (g >= 0) src = g;
      }
      voff[rt][k] = (unsigned)src * CBYTES + hi * 16;
    }
  }

  const char* abase = (const char*)inb;
  auto loadA = [&](int s, int rt, int ksub) -> bf16x8 {
    int k = s / KPERK, c32 = s % KPERK;              // compile-time under unroll
    return *reinterpret_cast<const bf16x8*>(abase + voff[rt][k] + c32 * 64 + ksub * 32);
  };
  const char* wbase = (const char*)Wp;
  auto loadBreg = [&](int s, int i) -> bf16x8 {      // wave w's frag 2w+i of step s
    return *reinterpret_cast<const bf16x8*>(wbase + ((size_t)s * 8 + 2 * w + i) * 1024 + lane * 16);
  };
  auto writeB = [&](int buf, int i, bf16x8 v) {
    *reinterpret_cast<bf16x8*>(&sB[buf][(2 * w + i) * 512 + lane * 8]) = v;
  };

  f32x16 acc[2][4];
  #pragma unroll
  for (int rt = 0; rt < 2; ++rt)
    #pragma unroll
    for (int ct = 0; ct < 4; ++ct)
      #pragma unroll
      for (int r = 0; r < 16; ++r) acc[rt][ct][r] = 0.f;

  // prologue: B(0)->LDS now; B(1) in regs; A(0) in regs (depth-1 queue)
  bf16x8 c0a = loadBreg(0, 0), c0b = loadBreg(0, 1);
  bf16x8 bqa = loadBreg(1, 0), bqb = loadBreg(1, 1);
  bf16x8 aq[2][2];
  #pragma unroll
  for (int rt = 0; rt < 2; ++rt) {
    aq[rt][0] = loadA(0, rt, 0); aq[rt][1] = loadA(0, rt, 1);
  }
  writeB(0, 0, c0a); writeB(0, 1, c0b);
  asm volatile("s_waitcnt lgkmcnt(0)" ::: "memory");
  asm volatile("s_barrier" ::: "memory");

  #pragma unroll
  for (int s = 0; s < KSTEPS; ++s) {
    const int cur = s % 3;
    bf16x8 nba = {}, nbb = {};
    if (s + 2 < KSTEPS) { nba = loadBreg(s + 2, 0); nbb = loadBreg(s + 2, 1); }
    bf16x8 na[2][2] = {};
    if (s + 1 < KSTEPS) {
      #pragma unroll
      for (int rt = 0; rt < 2; ++rt) {
        na[rt][0] = loadA(s + 1, rt, 0); na[rt][1] = loadA(s + 1, rt, 1);
      }
    }

    bf16x8 bb0[4];
    #pragma unroll
    for (int f = 0; f < 4; ++f)
      bb0[f] = *reinterpret_cast<const bf16x8*>(&sB[cur][f * 512 + lane * 8]);

    __builtin_amdgcn_s_setprio(1);
    #pragma unroll
    for (int ct = 0; ct < 4; ++ct) {
      acc[0][ct] = __builtin_amdgcn_mfma_f32_32x32x16_bf16(aq[0][0], bb0[ct], acc[0][ct], 0, 0, 0);
      acc[1][ct] = __builtin_amdgcn_mfma_f32_32x32x16_bf16(aq[1][0], bb0[ct], acc[1][ct], 0, 0, 0);
    }
    bf16x8 bb1[4];
    #pragma unroll
    for (int f = 0; f < 4; ++f)
      bb1[f] = *reinterpret_cast<const bf16x8*>(&sB[cur][(4 + f) * 512 + lane * 8]);
    #pragma unroll
    for (int ct = 0; ct < 4; ++ct) {
      acc[0][ct] = __builtin_amdgcn_mfma_f32_32x32x16_bf16(aq[0][1], bb1[ct], acc[0][ct], 0, 0, 0);
      acc[1][ct] = __builtin_amdgcn_mfma_f32_32x32x16_bf16(aq[1][1], bb1[ct], acc[1][ct], 0, 0, 0);
    }
    __builtin_amdgcn_s_setprio(0);

    if (s + 1 < KSTEPS) {               // stage B(s+1) into LDS
      writeB((s + 1) % 3, 0, bqa); writeB((s + 1) % 3, 1, bqb);
    }
    asm volatile("s_waitcnt lgkmcnt(0)" ::: "memory");
    asm volatile("s_barrier" ::: "memory");

    bqa = nba; bqb = nbb;
    #pragma unroll
    for (int rt = 0; rt < 2; ++rt) {
      aq[rt][0] = na[rt][0]; aq[rt][1] = na[rt][1];
    }
  }

  // epilogue: bias + store + fused BN stats partials
  // C/D: col = ct*32 + l31, row = row0 + w*64 + rt*32 + (reg&3) + 8*(reg>>2) + 4*hi
  #pragma unroll
  for (int ct = 0; ct < 4; ++ct) {
    int col = ct * 32 + l31;
    float bv = bias[col];
    float s = 0.f, q = 0.f;
    #pragma unroll
    for (int rt = 0; rt < 2; ++rt)
      #pragma unroll
      for (int reg = 0; reg < 16; ++reg) {
        int row = row0 + w * 64 + rt * 32 + (reg & 3) + 8 * (reg >> 2) + 4 * hi;
        float v = acc[rt][ct][reg] + bv;
        outb[(size_t)row * 128 + col] = f2bf(v);
        s += v; q = fmaf(v, v, q);
      }
    s += __shfl_xor(s, 32); q += __shfl_xor(q, 32);
    if (hi == 0) { sred[0][w][ct][l31] = s; sred[1][w][ct][l31] = q; }
  }
  __syncthreads();
  if (tid < 128) {                     // col == tid
    int ct = tid >> 5, c = tid & 31;
    float s = sred[0][0][ct][c] + sred[0][1][ct][c] +
              sred[0][2][ct][c] + sred[0][3][ct][c];
    float q = sred[1][0][ct][c] + sred[1][1][ct][c] +
              sred[1][2][ct][c] + sred[1][3][ct][c];
    pbuf[(size_t)tid * nblk + bid]         = s;
    pbuf[(size_t)(128 + tid) * nblk + bid] = q;
  }
}

// ------------------------------------------------- reduce stats partials + BN finalize
__global__ __launch_bounds__(256) void reduce_final(const float* __restrict__ pbuf,
                                                    int nblk,
                                                    const float* __restrict__ g,
                                                    const float* __restrict__ be,
                                                    int n,
                                                    float* __restrict__ scale,
                                                    float* __restrict__ shiftv) {
  const int c = blockIdx.x;
  const float* ps = pbuf + (size_t)c * nblk;
  const float* pq = pbuf + (size_t)(128 + c) * nblk;
  float s = 0.f, q = 0.f;
  for (int i = threadIdx.x; i < nblk; i += 256) { s += ps[i]; q += pq[i]; }
  __shared__ float ls[256], lq[256];
  ls[threadIdx.x] = s; lq[threadIdx.x] = q;
  __syncthreads();
  for (int o = 128; o > 0; o >>= 1) {
    if (threadIdx.x < o) {
      ls[threadIdx.x] += ls[threadIdx.x + o];
      lq[threadIdx.x] += lq[threadIdx.x + o];
    }
    __syncthreads();
  }
  if (threadIdx.x == 0) {
    float inv_n = 1.f / (float)n;
    float mu  = ls[0] * inv_n;
    float var = lq[0] * inv_n - mu * mu;
    float sc  = g[c] * rsqrtf(var + 1e-5f);
    scale[c]  = sc;
    shiftv[c] = be[c] - mu * sc;
  }
}

// ------------------------------------------------- in-place BN+ReLU on bf16 [n][128]
__global__ __launch_bounds__(256) void apply_bn(u16* __restrict__ f,
                                                const float* __restrict__ scale,
                                                const float* __restrict__ shiftv,
                                                int n) {
  long i = (long)blockIdx.x * 256 + threadIdx.x;   // one uint4 (8 elems) each
  long total = (long)n * 16;                        // n*128/8
  uint4* p = reinterpret_cast<uint4*>(f);
  if (i < total) {
    uint4 u = p[i];
    int c0 = (int)(i & 15) * 8;
    unsigned in4[4] = {u.x, u.y, u.z, u.w};
    unsigned r4[4];
    #pragma unroll
    for (int q = 0; q < 4; ++q) {
      float lo = bf2f((u16)(in4[q] & 0xffffu));
      float hi = bf2f((u16)(in4[q] >> 16));
      lo = fmaxf(lo * scale[c0 + 2*q]     + shiftv[c0 + 2*q],     0.f);
      hi = fmaxf(hi * scale[c0 + 2*q + 1] + shiftv[c0 + 2*q + 1], 0.f);
      r4[q] = (unsigned)f2bf(lo) | ((unsigned)f2bf(hi) << 16);
    }
    p[i] = make_uint4(r4[0], r4[1], r4[2], r4[3]);
  } else if (i < total + 16) {                      // zero row n (128 ch)
    p[i] = make_uint4(0, 0, 0, 0);
  }
}

// ---------------------------------------------------------------- pooling
__global__ __launch_bounds__(256) void scan_bsum(const int* __restrict__ flags,
                                                 int* __restrict__ bsum) {
  __shared__ int s[256];
  int t = threadIdx.x;
  s[t] = flags[blockIdx.x * 256 + t];
  __syncthreads();
  for (int o = 128; o > 0; o >>= 1) {
    if (t < o) s[t] += s[t + o];
    __syncthreads();
  }
  if (t == 0) bsum[blockIdx.x] = s[0];
}

__global__ __launch_bounds__(1024) void scan_offsets(const int* __restrict__ bsum,
                                                     int* __restrict__ boff) {
  __shared__ int s[1024];
  int t = threadIdx.x;
  int orig = bsum[t];
  s[t] = orig;
  __syncthreads();
  for (int o = 1; o < 1024; o <<= 1) {
    int v = (t >= o) ? s[t - o] : 0;
    __syncthreads();
    s[t] += v;
    __syncthreads();
  }
  boff[t] = s[t] - orig;   // exclusive
}

__global__ __launch_bounds__(256) void emit_uniq(const int* __restrict__ flags,
                                                 const int* __restrict__ boff,
                                                 int* __restrict__ cellOf,
                                                 float* __restrict__ out_uniq) {
  __shared__ int s[256];
  int t = threadIdx.x;
  int cell = blockIdx.x * 256 + t;
  int f = flags[cell];
  s[t] = f;
  __syncthreads();
  for (int o = 1; o < 256; o <<= 1) {
    int v = (t >= o) ? s[t - o] : 0;
    __syncthreads();
    s[t] += v;
    __syncthreads();
  }
  if (f) {
    int r = boff[blockIdx.x] + s[t] - f;
    cellOf[r] = cell;
    out_uniq[(size_t)r * 3 + 0] = (float)(cell >> 16);
    out_uniq[(size_t)r * 3 + 1] = (float)((cell >> 8) & 255);
    out_uniq[(size_t)r * 3 + 2] = (float)(cell & 255);
  }
}

// rank-compacted max pool: 16 lanes per cell, ushort8 (16B) row loads,
// grid-stride over ranks. BN applied via slope-sign max/min select.
__global__ __launch_bounds__(256) void pool2(const int* __restrict__ cellOf,
                                             const int* __restrict__ grid,
                                             const u16* __restrict__ f2,
                                             const float* __restrict__ scale,
                                             const float* __restrict__ shiftv,
                                             float* __restrict__ out_pooled, int U) {
  __shared__ float s_sc[128], s_sh[128];
  for (int c = threadIdx.x; c < 128; c += 256) { s_sc[c] = scale[c]; s_sh[c] = shiftv[c]; }
  __syncthreads();
  const int cslot = threadIdx.x >> 4;
  const int l16   = threadIdx.x & 15;
  const int c0    = l16 * 8;
  for (int base = blockIdx.x * 16; base < U; base += (int)gridDim.x * 16) {
    int rank = base + cslot;
    if (rank >= U) continue;
    int cell = cellOf[rank];
    int b = cell >> 16, y2 = (cell >> 8) & 255, x2 = cell & 255;
    int gb = (b * HH + y2 * 2) * WW + x2 * 2;
    int ss[4];
    ss[0] = grid[gb];      ss[1] = grid[gb + 1];
    ss[2] = grid[gb + WW]; ss[3] = grid[gb + WW + 1];
    float mx[8], mn[8];
    #pragma unroll
    for (int j = 0; j < 8; ++j) { mx[j] = -3.4e38f; mn[j] = 3.4e38f; }
    #pragma unroll
    for (int d = 0; d < 4; ++d) {
      int s = ss[d];
      if (s < 0) continue;
      uint4 u = *reinterpret_cast<const uint4*>(f2 + (size_t)s * 128 + c0);
      unsigned uu[4] = {u.x, u.y, u.z, u.w};
      #pragma unroll
      for (int q = 0; q < 4; ++q) {
        float lo = bf2f((u16)(uu[q] & 0xffffu));
        float hi = bf2f((u16)(uu[q] >> 16));
        mx[2*q]   = fmaxf(mx[2*q], lo);   mn[2*q]   = fminf(mn[2*q], lo);
        mx[2*q+1] = fmaxf(mx[2*q+1], hi); mn[2*q+1] = fminf(mn[2*q+1], hi);
      }
    }
    float o[8];
    #pragma unroll
    for (int j = 0; j < 8; ++j) {
      float sc = s_sc[c0 + j], sh = s_sh[c0 + j];
      float v = (sc >= 0.f) ? mx[j] : mn[j];
      o[j] = fmaxf(v * sc + sh, 0.f);
    }
    float4* op = reinterpret_cast<float4*>(out_pooled + (size_t)rank * 128 + c0);
    op[0] = make_float4(o[0], o[1], o[2], o[3]);
    op[1] = make_float4(o[4], o[5], o[6], o[7]);
  }
}

// ---------------------------------------------------------------- launch
extern "C" void kernel_launch(void* const* d_in, const int* in_sizes, int n_in,
                              void* d_out, int out_size, void* d_ws, size_t ws_size,
                              hipStream_t stream) {
  (void)n_in; (void)ws_size;
  const int*   coords = (const int*)  d_in[0];
  const float* feats  = (const float*)d_in[1];
  const float* W1     = (const float*)d_in[2];
  const float* b1     = (const float*)d_in[3];
  const float* g1     = (const float*)d_in[4];
  const float* be1    = (const float*)d_in[5];
  const float* W2     = (const float*)d_in[6];
  const float* b2     = (const float*)d_in[7];
  const float* g2     = (const float*)d_in[8];
  const float* be2    = (const float*)d_in[9];

  const int n = in_sizes[0] / 3;          // 262144 (multiple of 256)
  const int U = out_size / 131;           // out = uniq (U,3) ++ pooled (U,128)
  const int nblk = n / 256;               // 1024

  char* wsp = (char*)d_ws;
  size_t off = 0;
  auto alloc = [&](size_t bytes) -> void* {
    void* p = wsp + off;
    off += (bytes + 255) & ~(size_t)255;
    return p;
  };
  int* grid = (int*)alloc(sizeof(int) * (size_t)NB * HH * WW);
  u16* f1   = (u16*)alloc(sizeof(u16) * (size_t)(n + 1) * 128);  // conv1 out / BN+ReLU in-place (+zero row)
  u16* breg = (u16*)alloc(sizeof(u16) * (size_t)n * 128);        // feats_bf first, later f2
  u16* fbf  = breg;                                              // bf16 feats [n+1][64]
  u16* f2   = breg;                                              // bf16 conv2 out [n][128]
  u16* Wp1  = (u16*)alloc(sizeof(u16) * 9 * 64 * 128);
  u16* Wp2  = (u16*)alloc(sizeof(u16) * 9 * 128 * 128);
  float* pbuf = (float*)alloc(sizeof(float) * 256 * (size_t)nblk);  // stats partials
  float* bnp  = (float*)alloc(sizeof(float) * 512);   // scale1 shift1 scale2 shift2
  int* flags  = (int*)alloc(sizeof(int) * (size_t)NB * 256 * 256);
  int* bsum   = (int*)alloc(sizeof(int) * 1024);
  int* boff   = (int*)alloc(sizeof(int) * 1024);
  int* cellOf = (int*)alloc(sizeof(int) * (size_t)n);

  float* scale1 = bnp,       *shift1 = bnp + 128;
  float* scale2 = bnp + 256, *shift2 = bnp + 384;

  hipMemsetAsync(grid, 0xFF, sizeof(int) * (size_t)NB * HH * WW, stream);
  hipMemsetAsync(flags, 0, sizeof(int) * (size_t)NB * 256 * 256, stream);

  build_grid_mark<<<(n + 255) / 256, 256, 0, stream>>>(coords, n, grid, flags);
  cvt_feats<<<(n * 16 + 16 + 255) / 256, 256, 0, stream>>>(feats, fbf, n);
  pack_w<64><<<9 * 64 * 128 / 256, 256, 0, stream>>>(W1, Wp1);
  pack_w<128><<<9 * 128 * 128 / 256, 256, 0, stream>>>(W2, Wp2);

  conv_mfma<64><<<nblk, 256, 0, stream>>>(fbf, Wp1, b1, coords, grid, f1, pbuf, n);
  reduce_final<<<128, 256, 0, stream>>>(pbuf, nblk, g1, be1, n, scale1, shift1);
  apply_bn<<<(n * 16 + 16 + 255) / 256, 256, 0, stream>>>(f1, scale1, shift1, n);

  conv_mfma<128><<<nblk, 256, 0, stream>>>(f1, Wp2, b2, coords, grid, f2, pbuf, n);
  reduce_final<<<128, 256, 0, stream>>>(pbuf, nblk, g2, be2, n, scale2, shift2);

  scan_bsum<<<1024, 256, 0, stream>>>(flags, bsum);
  scan_offsets<<<1, 1024, 0, stream>>>(bsum, boff);

  float* out_f = (float*)d_out;
  emit_uniq<<<1024, 256, 0, stream>>>(flags, boff, cellOf, out_f);
  pool2<<<2048, 256, 0, stream>>>(cellOf, grid, f2, scale2, shift2,
                                  out_f + (size_t)U * 3, U);
}